// Round 17
// baseline (529.243 us; speedup 1.0000x reference)
//
#include <hip/hip_runtime.h>
#include <hip/hip_bf16.h>

#define NN 50000
#define NE 800000
#define MP 50048           // 391*128 padded rows
#define NBLK 196           // ceil(NN/256)

typedef __attribute__((ext_vector_type(8))) short short8;
typedef __attribute__((ext_vector_type(4))) float f32x4;

__device__ __forceinline__ float b2f(__hip_bfloat16 x) { return __bfloat162float(x); }
__device__ __forceinline__ __hip_bfloat16 f2b(float x) { return __float2bfloat16(x); }
__device__ __forceinline__ float bu2f(unsigned short u) { return __uint_as_float(((unsigned)u) << 16); }
__device__ __forceinline__ unsigned short f2bu(float x) { __hip_bfloat16 b = f2b(x); return *(unsigned short*)&b; }
__device__ __forceinline__ float sigm(float x) { return 1.f / (1.f + __expf(-x)); }
__device__ __forceinline__ float leaky(float x) { return x >= 0.f ? x : 0.2f * x; }

__device__ __forceinline__ void gload16(const void* g, void* l) {
  __builtin_amdgcn_global_load_lds((__attribute__((address_space(1))) void*)(g),
                                   (__attribute__((address_space(3))) void*)(l), 16, 0, 0);
}

__global__ void diag_kernel(float* out, float v) { out[0] = v; }

__global__ void zero_i32(int* p, int n) {
  int i = blockIdx.x * 256 + threadIdx.x;
  if (i < n) p[i] = 0;
}

__global__ void conv_kernel(const float* __restrict__ in, __hip_bfloat16* __restrict__ out, int n) {
  for (int i = blockIdx.x * blockDim.x + threadIdx.x; i < n; i += gridDim.x * blockDim.x)
    out[i] = f2b(in[i]);
}

__global__ void conv4_kernel(const float* __restrict__ in, __hip_bfloat16* __restrict__ out, int n4) {
  int i = blockIdx.x * 256 + threadIdx.x;
  if (i >= n4) return;
  float4 v = ((const float4*)in)[i];
  ushort4 o;
  o.x = f2bu(v.x); o.y = f2bu(v.y); o.z = f2bu(v.z); o.w = f2bu(v.w);
  ((ushort4*)out)[i] = o;
}

__global__ void conv_gruw(const float* __restrict__ p0, const float* __restrict__ p1,
                          const float* __restrict__ p2, const float* __restrict__ p3,
                          __hip_bfloat16* __restrict__ out) {
  int idx = blockIdx.x * 256 + threadIdx.x;  // 786432 total
  int w = idx / 196608, r = idx - w * 196608;
  const float* s = (w == 0) ? p0 : (w == 1) ? p1 : (w == 2) ? p2 : p3;
  out[idx] = f2b(s[r]);
}

__global__ void conv_strided(const float* __restrict__ in, __hip_bfloat16* __restrict__ out,
                             int rows, int cols, int ld, int coff) {
  int idx = blockIdx.x * 256 + threadIdx.x;
  if (idx >= rows * cols) return;
  int r = idx / cols, c = idx - r * cols;
  out[idx] = f2b(in[(size_t)r * ld + coff + c]);
}

// ==================== burst-staged GEMM (tile 128x128, BK=128 phases) ====================
#define EPI_ESED 0
#define EPI_OUT  1

template <int EPI, bool DUAL>
__global__ __launch_bounds__(256, 2) void gemmF(
    const __hip_bfloat16* __restrict__ A1, const __hip_bfloat16* __restrict__ B1,
    const __hip_bfloat16* __restrict__ A2, const __hip_bfloat16* __restrict__ B2,
    void* __restrict__ Cv, int M, int N,
    const float* __restrict__ bi, const float* __restrict__ bh,
    float* __restrict__ ESp, float* __restrict__ EDp) {
  __shared__ __align__(16) short smem[32768];  // A[128][128] + B[128][128]
  const int tid = threadIdx.x;
  const int wid = tid >> 6, lane = tid & 63;

  // XCD-chunked bijective swizzle (m204)
  const int NW = gridDim.x * gridDim.y;
  const int wg = blockIdx.x + gridDim.x * blockIdx.y;
  const int q = NW >> 3, r8 = NW & 7;
  const int xcd = wg & 7, jj = wg >> 3;
  const int wid2 = (xcd < r8 ? xcd * (q + 1) : r8 * (q + 1) + (xcd - r8) * q) + jj;
  const int m0 = (wid2 / gridDim.x) * 128, n0 = (wid2 % gridDim.x) * 128;

  const int NPH = DUAL ? 4 : 2;
  f32x4 acc[2][8];
#pragma unroll
  for (int rf = 0; rf < 2; ++rf)
#pragma unroll
    for (int cf = 0; cf < 8; ++cf) acc[rf][cf] = (f32x4)0.f;

  for (int p = 0; p < NPH; ++p) {
    const __hip_bfloat16* A = (DUAL && p >= 2) ? A2 : A1;
    const __hip_bfloat16* B = (DUAL && p >= 2) ? B2 : B1;
    const int k0 = (p & 1) * 128;
#pragma unroll
    for (int i = 0; i < 8; ++i) {
      int qi = wid * 8 + i;
      int rl = qi * 4 + (lane >> 4);
      int sl = (lane & 15) ^ (rl & 15);
      gload16(A + (size_t)(m0 + rl) * 256 + k0 + sl * 8, &smem[qi * 512]);
      gload16(B + (size_t)(n0 + rl) * 256 + k0 + sl * 8, &smem[16384 + qi * 512]);
    }
    asm volatile("s_waitcnt vmcnt(0)" ::: "memory");
    __builtin_amdgcn_s_barrier();
    __builtin_amdgcn_sched_barrier(0);
#pragma unroll
    for (int kc = 0; kc < 4; ++kc) {
      const int sl = ((kc * 4 + (lane >> 4)) ^ (lane & 15)) * 8;
      short8 af[2];
#pragma unroll
      for (int rf = 0; rf < 2; ++rf)
        af[rf] = *(const short8*)&smem[(wid * 32 + rf * 16 + (lane & 15)) * 128 + sl];
#pragma unroll
      for (int cf = 0; cf < 8; ++cf) {
        short8 bf = *(const short8*)&smem[16384 + (cf * 16 + (lane & 15)) * 128 + sl];
#pragma unroll
        for (int rf = 0; rf < 2; ++rf)
          acc[rf][cf] = __builtin_amdgcn_mfma_f32_16x16x32_bf16(af[rf], bf, acc[rf][cf], 0, 0, 0);
      }
    }
    asm volatile("s_waitcnt lgkmcnt(0)" ::: "memory");
    __builtin_amdgcn_sched_barrier(0);
    __builtin_amdgcn_s_barrier();
  }

  const int rowb = m0 + wid * 32 + (lane >> 4) * 4;
  const int colb = n0 + (lane & 15);

  if constexpr (EPI == EPI_ESED) {
    const int head = n0 >> 7;
#pragma unroll
    for (int rf = 0; rf < 2; ++rf) {
#pragma unroll
      for (int rr = 0; rr < 4; ++rr) {
        const int row = rowb + rf * 16 + rr;
        float ps = 0.f, pd = 0.f;
#pragma unroll
        for (int cf = 0; cf < 8; ++cf) {
          const int col = colb + cf * 16;
          float v = acc[rf][cf][rr];
          if (row < M) ((__hip_bfloat16*)Cv)[(size_t)row * N + col] = f2b(v);
          ps += v * bi[col];
          pd += v * bh[col];
        }
#pragma unroll
        for (int o = 8; o >= 1; o >>= 1) {
          ps += __shfl_xor(ps, o, 64);
          pd += __shfl_xor(pd, o, 64);
        }
        if ((lane & 15) == 0 && row < M) {
          ESp[row * 2 + head] = ps;
          EDp[row * 2 + head] = pd;
        }
      }
    }
    return;
  }
#pragma unroll
  for (int rf = 0; rf < 2; ++rf)
#pragma unroll
    for (int cf = 0; cf < 8; ++cf) {
      const int col = colb + cf * 16;
#pragma unroll
      for (int rr = 0; rr < 4; ++rr) {
        const int row = rowb + rf * 16 + rr;
        if (row < M) ((float*)Cv)[(size_t)row * 256 + col] = acc[rf][cf][rr];
      }
    }
}

// ==================== gruF: fused GRU step, 128rows x 32cols, rf=2 ====================
// r16 proved occupancy is the lever (64 VGPR/32KB -> 40% occ, 144us). Now fix the next
// limit: LDS-read throughput (13 reads / 12 MFMAs at rf=1). rf=2 with 32-col slices:
// 8 reads / 12 MFMAs per kc, acc stays 16 f32x4 (64 VGPR), LDS 28KB. Output staged
// through LDS (reusing A region after the final barrier) -> 64B/row coalesced stores
// (fixes the 3x write amplification seen as WRITE_SIZE 75MB vs 25.6 ideal).
template <int STEP>
__global__ __launch_bounds__(256) void gruF(
    const __hip_bfloat16* __restrict__ hF, const __hip_bfloat16* __restrict__ WiF,
    const __hip_bfloat16* __restrict__ hpF, const __hip_bfloat16* __restrict__ WhF,
    const float* __restrict__ biF, const float* __restrict__ bhF,
    __hip_bfloat16* __restrict__ outF,
    const __hip_bfloat16* __restrict__ hB, const __hip_bfloat16* __restrict__ WiB,
    const __hip_bfloat16* __restrict__ hpB, const __hip_bfloat16* __restrict__ WhB,
    const float* __restrict__ biB, const float* __restrict__ bhB,
    __hip_bfloat16* __restrict__ outB) {
  __shared__ __align__(16) short smem[14336];  // A[128][64] (8192) + B[96][64] (6144)
  const int tid = threadIdx.x;
  const int wid = tid >> 6, lane = tid & 63;

  // XCD swizzle; 16 slices (8 col x 2 dir) of one row-group are consecutive -> same XCD
  const int NW = gridDim.x * gridDim.y;   // 16 * 391 (divisible by 8)
  const int wg = blockIdx.x + gridDim.x * blockIdx.y;
  const int q = NW >> 3, r8 = NW & 7;
  const int xcd = wg & 7, jj = wg >> 3;
  const int wid2 = (xcd < r8 ? xcd * (q + 1) : r8 * (q + 1) + (xcd - r8) * q) + jj;
  const int bx2 = wid2 & 15;
  const int m0 = (wid2 >> 4) * 128;
  const int dir = bx2 >> 3;
  const int nc0 = (bx2 & 7) * 32;

  const __hip_bfloat16* Ah = dir ? hB : hF;
  const __hip_bfloat16* Wi = dir ? WiB : WiF;
  const __hip_bfloat16* Ahp = dir ? hpB : hpF;
  const __hip_bfloat16* Wh = dir ? WhB : WhF;
  const float* bi = dir ? biB : biF;
  const float* bh = dir ? bhB : bhF;
  __hip_bfloat16* outp = dir ? outB : outF;

  f32x4 acc[2][6];    // [rf][g*2+cf]: g 0=r, 1=z, 2=n_i
  f32x4 accNh[2][2];
#pragma unroll
  for (int rf = 0; rf < 2; ++rf) {
#pragma unroll
    for (int j = 0; j < 6; ++j) acc[rf][j] = (f32x4)0.f;
#pragma unroll
    for (int j = 0; j < 2; ++j) accNh[rf][j] = (f32x4)0.f;
  }

  auto stage = [&](const __hip_bfloat16* A, const __hip_bfloat16* W, int k0) {
    // A: 128 rows x 64 shorts = 16 issues (4/wave); issue = 8 rows x 8 perm-chunks
#pragma unroll
    for (int i = 0; i < 4; ++i) {
      int qi = wid * 4 + i;
      int rl = qi * 8 + (lane >> 3);
      int sl = (lane & 7) ^ (rl & 7);
      gload16(A + (size_t)(m0 + rl) * 256 + k0 + sl * 8, &smem[qi * 512]);
    }
    // B: 96 rows (3 gates x 32 cols) = 12 issues (3/wave); W row = (rl>>5)*256+nc0+(rl&31)
#pragma unroll
    for (int i = 0; i < 3; ++i) {
      int qi = wid * 3 + i;
      int rl = qi * 8 + (lane >> 3);
      int wrow = (rl >> 5) * 256 + nc0 + (rl & 31);
      int sl = (lane & 7) ^ (rl & 7);
      gload16(W + (size_t)wrow * 256 + k0 + sl * 8, &smem[8192 + qi * 512]);
    }
  };

  auto computeP = [&](auto PASSC) {
    constexpr int PASS = decltype(PASSC)::value;
#pragma unroll
    for (int kc = 0; kc < 2; ++kc) {
      short8 af[2];
#pragma unroll
      for (int rf = 0; rf < 2; ++rf) {
        const int arow = wid * 32 + rf * 16 + (lane & 15);
        const int pa = ((kc * 4 + (lane >> 4)) ^ (arow & 7)) * 8;
        af[rf] = *(const short8*)&smem[arow * 64 + pa];
      }
#pragma unroll
      for (int j = 0; j < 6; ++j) {
        const int brow = j * 16 + (lane & 15);
        const int pb = ((kc * 4 + (lane >> 4)) ^ (brow & 7)) * 8;
        short8 bf = *(const short8*)&smem[8192 + brow * 64 + pb];
#pragma unroll
        for (int rf = 0; rf < 2; ++rf) {
          if constexpr (PASS == 1) {
            if (j >= 4)
              accNh[rf][j - 4] = __builtin_amdgcn_mfma_f32_16x16x32_bf16(af[rf], bf, accNh[rf][j - 4], 0, 0, 0);
            else
              acc[rf][j] = __builtin_amdgcn_mfma_f32_16x16x32_bf16(af[rf], bf, acc[rf][j], 0, 0, 0);
          } else {
            acc[rf][j] = __builtin_amdgcn_mfma_f32_16x16x32_bf16(af[rf], bf, acc[rf][j], 0, 0, 0);
          }
        }
      }
    }
  };

  const int NPH = (STEP == 1) ? 4 : 8;
  for (int p = 0; p < NPH; ++p) {
    const int k0 = (p & 3) * 64;
    if (STEP == 2 && p >= 4) stage(Ahp, Wh, k0);
    else stage(Ah, Wi, k0);
    asm volatile("s_waitcnt vmcnt(0)" ::: "memory");
    __builtin_amdgcn_s_barrier();
    __builtin_amdgcn_sched_barrier(0);
    if (STEP == 2 && p >= 4) computeP(std::integral_constant<int, 1>{});
    else computeP(std::integral_constant<int, 0>{});
    asm volatile("s_waitcnt lgkmcnt(0)" ::: "memory");
    __builtin_amdgcn_sched_barrier(0);
    __builtin_amdgcn_s_barrier();
  }

  // epilogue: gate math -> LDS (reuse A region, 128x32 shorts), then coalesced stores
#pragma unroll
  for (int cf = 0; cf < 2; ++cf) {
    const int col = nc0 + cf * 16 + (lane & 15);
    const int col_l = cf * 16 + (lane & 15);
    const float brz = bi[col] + bh[col];
    const float bzz = bi[256 + col] + bh[256 + col];
    const float bin = bi[512 + col];
    const float bhn = bh[512 + col];
#pragma unroll
    for (int rf = 0; rf < 2; ++rf) {
#pragma unroll
      for (int rr = 0; rr < 4; ++rr) {
        const int row_l = wid * 32 + rf * 16 + (lane >> 4) * 4 + rr;
        const int row = m0 + row_l;
        float r_ = sigm(acc[rf][cf][rr] + brz);
        float z_ = sigm(acc[rf][2 + cf][rr] + bzz);
        float o;
        if constexpr (STEP == 1) {
          float n_ = tanhf(acc[rf][4 + cf][rr] + bin + r_ * bhn);
          o = (1.f - z_) * n_;
        } else {
          float n_ = tanhf(acc[rf][4 + cf][rr] + bin + r_ * (accNh[rf][cf][rr] + bhn));
          float hp = (row < NN) ? b2f(Ahp[(size_t)row * 256 + col]) : 0.f;
          o = hp + (1.f - z_) * n_ + z_ * hp;
        }
        smem[row_l * 32 + col_l] = (short)f2bu(o);
      }
    }
  }
  __syncthreads();
  // 512 chunks of 8 shorts: row 64B written in one 4-thread burst
#pragma unroll
  for (int it = 0; it < 2; ++it) {
    int c = tid + it * 256;
    int row_l = c >> 2, colc = (c & 3) * 8;
    int row = m0 + row_l;
    if (row < NN)
      *(short8*)&outp[(size_t)row * 256 + nc0 + colc] = *(const short8*)&smem[row_l * 32 + colc];
  }
}

// ---------------- CSR build ----------------
__global__ void hist_kernel(const int* __restrict__ dst, int* __restrict__ deg, int ne) {
  for (int e = blockIdx.x * blockDim.x + threadIdx.x; e < ne; e += gridDim.x * blockDim.x)
    atomicAdd(&deg[dst[e]], 1);
}

__global__ void scan1(const int* __restrict__ deg, int* __restrict__ bsum, int n) {
  __shared__ int sd[256];
  int idx = blockIdx.x * 256 + threadIdx.x;
  sd[threadIdx.x] = (idx < n) ? deg[idx] : 0;
  __syncthreads();
  for (int off = 128; off > 0; off >>= 1) {
    if (threadIdx.x < off) sd[threadIdx.x] += sd[threadIdx.x + off];
    __syncthreads();
  }
  if (threadIdx.x == 0) bsum[blockIdx.x] = sd[0];
}

__global__ void scan2(const int* __restrict__ bsum, int* __restrict__ boff, int nb) {
  __shared__ int s[256];
  int t = threadIdx.x;
  int v0 = (t < nb) ? bsum[t] : 0;
  s[t] = v0;
  __syncthreads();
  for (int off = 1; off < 256; off <<= 1) {
    int x = (t >= off) ? s[t - off] : 0;
    __syncthreads();
    s[t] += x;
    __syncthreads();
  }
  if (t < nb) boff[t] = s[t] - v0;
}

__global__ void scan3(const int* __restrict__ deg, const int* __restrict__ boff,
                      int* __restrict__ row_ptr, int* __restrict__ cursor, int n, int ne) {
  __shared__ int s[256];
  int t = threadIdx.x;
  int idx = blockIdx.x * 256 + t;
  int v = (idx < n) ? deg[idx] : 0;
  s[t] = v;
  __syncthreads();
  for (int off = 1; off < 256; off <<= 1) {
    int x = (t >= off) ? s[t - off] : 0;
    __syncthreads();
    s[t] += x;
    __syncthreads();
  }
  if (idx < n) {
    int val = boff[blockIdx.x] + s[t] - v;
    row_ptr[idx] = val;
    cursor[idx] = val;
  }
  if (idx == n) row_ptr[n] = ne;
}

__global__ void scatter_kernel(const int* __restrict__ src, const int* __restrict__ dst,
                               int* __restrict__ cursor, int* __restrict__ srcs, int ne) {
  for (int e = blockIdx.x * blockDim.x + threadIdx.x; e < ne; e += gridDim.x * blockDim.x) {
    int p = atomicAdd(&cursor[dst[e]], 1);
    srcs[p] = src[e];
  }
}

// ---------------- GAT aggregation: one wave per node ----------------
__device__ __forceinline__ void onl_upd(float& m, float& s, float v) {
  if (v <= m) {
    s += __expf(v - m);
  } else {
    s = s * __expf(m - v) + 1.f;
    m = v;
  }
}

__global__ __launch_bounds__(256) void gat_agg_wave(const int* __restrict__ row_ptr,
                                                    const int* __restrict__ srcs,
                                                    const float* __restrict__ es,
                                                    const float* __restrict__ ed,
                                                    const __hip_bfloat16* __restrict__ z,
                                                    __hip_bfloat16* __restrict__ hout) {
  int node = blockIdx.x * 4 + (threadIdx.x >> 6);
  int lane = threadIdx.x & 63;
  if (node >= NN) return;
  ushort4* outp = (ushort4*)&hout[(size_t)node * 256 + lane * 4];
  int start = row_ptr[node], end = row_ptr[node + 1];
  int deg = end - start;
  if (deg == 0) {
    *outp = make_ushort4(0, 0, 0, 0);
    return;
  }
  float ed0 = ed[node * 2], ed1 = ed[node * 2 + 1];
  int h = lane >> 5;
  float a0 = 0.f, a1 = 0.f, a2 = 0.f, a3 = 0.f;

  if (deg <= 64) {
    int sn = 0;
    float l0 = -1e30f, l1 = -1e30f;
    if (lane < deg) {
      sn = srcs[start + lane];
      float2 ee = *(const float2*)&es[sn * 2];
      l0 = leaky(ee.x + ed0);
      l1 = leaky(ee.y + ed1);
    }
    float m0 = l0, m1 = l1;
#pragma unroll
    for (int off = 32; off > 0; off >>= 1) {
      m0 = fmaxf(m0, __shfl_xor(m0, off, 64));
      m1 = fmaxf(m1, __shfl_xor(m1, off, 64));
    }
    float p0 = (lane < deg) ? __expf(l0 - m0) : 0.f;
    float p1 = (lane < deg) ? __expf(l1 - m1) : 0.f;
    float s0 = p0, s1 = p1;
#pragma unroll
    for (int off = 32; off > 0; off >>= 1) {
      s0 += __shfl_xor(s0, off, 64);
      s1 += __shfl_xor(s1, off, 64);
    }
    float w0 = p0 / s0, w1 = p1 / s1;
    const size_t zlo = lane * 4;
    int e = 0;
    for (; e + 4 <= deg; e += 4) {
      int sa = __shfl(sn, e, 64), sb = __shfl(sn, e + 1, 64);
      int sc = __shfl(sn, e + 2, 64), sd = __shfl(sn, e + 3, 64);
      float wa0 = __shfl(w0, e, 64),     wa1 = __shfl(w1, e, 64);
      float wb0 = __shfl(w0, e + 1, 64), wb1 = __shfl(w1, e + 1, 64);
      float wc0 = __shfl(w0, e + 2, 64), wc1 = __shfl(w1, e + 2, 64);
      float wd0 = __shfl(w0, e + 3, 64), wd1 = __shfl(w1, e + 3, 64);
      float wa = h ? wa1 : wa0;
      float wb = h ? wb1 : wb0;
      float wc = h ? wc1 : wc0;
      float wd = h ? wd1 : wd0;
      ushort4 za = *(const ushort4*)&z[(size_t)sa * 256 + zlo];
      ushort4 zb = *(const ushort4*)&z[(size_t)sb * 256 + zlo];
      ushort4 zc = *(const ushort4*)&z[(size_t)sc * 256 + zlo];
      ushort4 zd = *(const ushort4*)&z[(size_t)sd * 256 + zlo];
      a0 = fmaf(wa, bu2f(za.x), a0); a1 = fmaf(wa, bu2f(za.y), a1);
      a2 = fmaf(wa, bu2f(za.z), a2); a3 = fmaf(wa, bu2f(za.w), a3);
      a0 = fmaf(wb, bu2f(zb.x), a0); a1 = fmaf(wb, bu2f(zb.y), a1);
      a2 = fmaf(wb, bu2f(zb.z), a2); a3 = fmaf(wb, bu2f(zb.w), a3);
      a0 = fmaf(wc, bu2f(zc.x), a0); a1 = fmaf(wc, bu2f(zc.y), a1);
      a2 = fmaf(wc, bu2f(zc.z), a2); a3 = fmaf(wc, bu2f(zc.w), a3);
      a0 = fmaf(wd, bu2f(zd.x), a0); a1 = fmaf(wd, bu2f(zd.y), a1);
      a2 = fmaf(wd, bu2f(zd.z), a2); a3 = fmaf(wd, bu2f(zd.w), a3);
    }
    for (; e < deg; ++e) {
      int sa = __shfl(sn, e, 64);
      float wa0 = __shfl(w0, e, 64), wa1 = __shfl(w1, e, 64);
      float wa = h ? wa1 : wa0;
      ushort4 za = *(const ushort4*)&z[(size_t)sa * 256 + zlo];
      a0 = fmaf(wa, bu2f(za.x), a0); a1 = fmaf(wa, bu2f(za.y), a1);
      a2 = fmaf(wa, bu2f(za.z), a2); a3 = fmaf(wa, bu2f(za.w), a3);
    }
  } else {
    float m0 = -1e30f, s0 = 0.f, m1 = -1e30f, s1 = 0.f;
    for (int i = start + lane; i < end; i += 64) {
      int sn = srcs[i];
      float e0 = es[sn * 2], e1 = es[sn * 2 + 1];
      onl_upd(m0, s0, leaky(e0 + ed0));
      onl_upd(m1, s1, leaky(e1 + ed1));
    }
#pragma unroll
    for (int off = 32; off > 0; off >>= 1) {
      float om0 = __shfl_xor(m0, off, 64), os0 = __shfl_xor(s0, off, 64);
      float om1 = __shfl_xor(m1, off, 64), os1 = __shfl_xor(s1, off, 64);
      float mm = fmaxf(m0, om0);
      s0 = s0 * __expf(m0 - mm) + os0 * __expf(om0 - mm);
      m0 = mm;
      mm = fmaxf(m1, om1);
      s1 = s1 * __expf(m1 - mm) + os1 * __expf(om1 - mm);
      m1 = mm;
    }
    float rm = h ? m1 : m0;
    float rsi = 1.f / (h ? s1 : s0);
    float edh = h ? ed1 : ed0;
    for (int e = start; e < end; ++e) {
      int sa = srcs[e];
      float2 ee = *(const float2*)&es[sa * 2];
      float w = __expf(leaky((h ? ee.y : ee.x) + edh) - rm) * rsi;
      ushort4 zv = *(const ushort4*)&z[(size_t)sa * 256 + lane * 4];
      a0 = fmaf(w, bu2f(zv.x), a0); a1 = fmaf(w, bu2f(zv.y), a1);
      a2 = fmaf(w, bu2f(zv.z), a2); a3 = fmaf(w, bu2f(zv.w), a3);
    }
  }
  ushort4 o;
  o.x = f2bu(fmaxf(a0, 0.f));
  o.y = f2bu(fmaxf(a1, 0.f));
  o.z = f2bu(fmaxf(a2, 0.f));
  o.w = f2bu(fmaxf(a3, 0.f));
  *outp = o;
}

// ---------------- host ----------------
extern "C" void kernel_launch(void* const* d_in, const int* in_sizes, int n_in,
                              void* d_out, int out_size, void* d_ws, size_t ws_size,
                              hipStream_t stream) {
  const float* in_feat = (const float*)d_in[0];
  const int* srcp = (const int*)d_in[1];
  const int* dstp = (const int*)d_in[2];
  const float* W1 = (const float*)d_in[3];
  const float* as1 = (const float*)d_in[4];
  const float* ad1 = (const float*)d_in[5];
  const float* W2 = (const float*)d_in[6];
  const float* as2 = (const float*)d_in[7];
  const float* ad2 = (const float*)d_in[8];
  const float* wi_f = (const float*)d_in[9];
  const float* wh_f = (const float*)d_in[10];
  const float* bi_f = (const float*)d_in[11];
  const float* bh_f = (const float*)d_in[12];
  const float* wi_b = (const float*)d_in[13];
  const float* wh_b = (const float*)d_in[14];
  const float* bi_b = (const float*)d_in[15];
  const float* bh_b = (const float*)d_in[16];
  // d_in[17] = s_w: dead (softmax over a singleton axis == 1.0)
  const float* lin_w = (const float*)d_in[18];
  (void)in_sizes; (void)n_in; (void)out_size;

  const size_t UNIT = (size_t)MP * 256 * 2;
  char* ws = (char*)d_ws;
  size_t off = 0;
  auto take = [&](size_t bytes) -> void* {
    void* p = ws + off;
    off += (bytes + 255) & ~(size_t)255;
    return p;
  };
  __hip_bfloat16* U0 = (__hip_bfloat16*)take(UNIT);      // x, then fsum
  __hip_bfloat16* U1 = (__hip_bfloat16*)take(UNIT * 2);  // z (GAT), then bsum
  __hip_bfloat16* h1 = (__hip_bfloat16*)take(UNIT);
  __hip_bfloat16* h2 = (__hip_bfloat16*)take(UNIT);
  __hip_bfloat16* hpF = (__hip_bfloat16*)take(UNIT);     // f0
  __hip_bfloat16* hpB = (__hip_bfloat16*)take(UNIT);     // b1
  __hip_bfloat16* wW1 = (__hip_bfloat16*)take(65536 * 2);
  __hip_bfloat16* wW2 = (__hip_bfloat16*)take(65536 * 2);
  __hip_bfloat16* wif = (__hip_bfloat16*)take(196608 * 2);  // conv_gruw order: wif,whf,wib,whb
  __hip_bfloat16* whf = (__hip_bfloat16*)take(196608 * 2);
  __hip_bfloat16* wib = (__hip_bfloat16*)take(196608 * 2);
  __hip_bfloat16* whb = (__hip_bfloat16*)take(196608 * 2);
  __hip_bfloat16* wlinA = (__hip_bfloat16*)take(65536 * 2);
  __hip_bfloat16* wlinB = (__hip_bfloat16*)take(65536 * 2);
  int* deg = (int*)take((size_t)NN * 4);
  float* es1 = (float*)take((size_t)NN * 2 * 4);
  float* ed1 = (float*)take((size_t)NN * 2 * 4);
  float* es2 = (float*)take((size_t)NN * 2 * 4);
  float* ed2 = (float*)take((size_t)NN * 2 * 4);
  int* cursor = (int*)take((size_t)NN * 4);
  int* row_ptr = (int*)take((size_t)(NN + 1) * 4);
  int* bsum = (int*)take(256 * 4);
  int* boff = (int*)take(256 * 4);
  int* srcs = (int*)take((size_t)NE * 4);

  if (off > ws_size) {
    diag_kernel<<<1, 1, 0, stream>>>((float*)d_out, (float)ws_size);
    return;
  }

  // conversions
  conv4_kernel<<<12500, 256, 0, stream>>>(in_feat, U0, NN * 64);
  conv_kernel<<<256, 256, 0, stream>>>(W1, wW1, 65536);
  conv_kernel<<<256, 256, 0, stream>>>(W2, wW2, 65536);
  conv_gruw<<<3072, 256, 0, stream>>>(wi_f, wh_f, wi_b, wh_b, wif);
  conv_strided<<<256, 256, 0, stream>>>(lin_w, wlinA, 256, 256, 512, 0);
  conv_strided<<<256, 256, 0, stream>>>(lin_w, wlinB, 256, 256, 512, 256);

  // zero deg + es/ed
  {
    int zw = (int)(((char*)ed2 - (char*)deg) / 4) + NN * 2;
    zero_i32<<<(zw + 255) / 256, 256, 0, stream>>>(deg, zw);
  }
  hist_kernel<<<1024, 256, 0, stream>>>(dstp, deg, NE);
  scan1<<<NBLK, 256, 0, stream>>>(deg, bsum, NN);
  scan2<<<1, 256, 0, stream>>>(bsum, boff, NBLK);
  scan3<<<NBLK, 256, 0, stream>>>(deg, boff, row_ptr, cursor, NN, NE);
  scatter_kernel<<<1024, 256, 0, stream>>>(srcp, dstp, cursor, srcs, NE);

  dim3 g2(2, MP / 128), gGRU(16, MP / 128);

  // GAT layer 1
  gemmF<EPI_ESED, false><<<g2, 256, 0, stream>>>(U0, wW1, nullptr, nullptr, U1, NN, 256,
                                                 as1, ad1, es1, ed1);
  gat_agg_wave<<<12500, 256, 0, stream>>>(row_ptr, srcs, es1, ed1, U1, h1);
  // GAT layer 2
  gemmF<EPI_ESED, false><<<g2, 256, 0, stream>>>(h1, wW2, nullptr, nullptr, U1, NN, 256,
                                                 as2, ad2, es2, ed2);
  gat_agg_wave<<<12500, 256, 0, stream>>>(row_ptr, srcs, es2, ed2, U1, h2);

  // GRU step 1 (both directions): f0 = step(0,h1) -> hpF ; b1 = step(0,h2) -> hpB
  gruF<1><<<gGRU, 256, 0, stream>>>(
      h1, wif, nullptr, nullptr, bi_f, bh_f, hpF,
      h2, wib, nullptr, nullptr, bi_b, bh_b, hpB);
  // GRU step 2 (both directions): fsum = f0 + step(f0,h2) -> U0 ; bsum = b1 + step(b1,h1) -> U1
  gruF<2><<<gGRU, 256, 0, stream>>>(
      h2, wif, hpF, whf, bi_f, bh_f, U0,
      h1, wib, hpB, whb, bi_b, bh_b, U1);

  // out = fsum@linA^T + bsum@linB^T
  gemmF<EPI_OUT, true><<<g2, 256, 0, stream>>>(U0, wlinA, U1, wlinB, d_out, NN, 256,
                                               nullptr, nullptr, nullptr, nullptr);
}

// Round 18
// 499.907 us; speedup vs baseline: 1.0587x; 1.0587x over previous
//
#include <hip/hip_runtime.h>
#include <hip/hip_bf16.h>

#define NN 50000
#define NE 800000
#define MP 50048           // 391*128 padded rows
#define NBLK 196           // ceil(NN/256)

typedef __attribute__((ext_vector_type(8))) short short8;
typedef __attribute__((ext_vector_type(4))) float f32x4;

__device__ __forceinline__ float b2f(__hip_bfloat16 x) { return __bfloat162float(x); }
__device__ __forceinline__ __hip_bfloat16 f2b(float x) { return __float2bfloat16(x); }
__device__ __forceinline__ float bu2f(unsigned short u) { return __uint_as_float(((unsigned)u) << 16); }
__device__ __forceinline__ unsigned short f2bu(float x) { __hip_bfloat16 b = f2b(x); return *(unsigned short*)&b; }
__device__ __forceinline__ float sigm(float x) { return 1.f / (1.f + __expf(-x)); }
__device__ __forceinline__ float leaky(float x) { return x >= 0.f ? x : 0.2f * x; }

__device__ __forceinline__ void gload16(const void* g, void* l) {
  __builtin_amdgcn_global_load_lds((__attribute__((address_space(1))) void*)(g),
                                   (__attribute__((address_space(3))) void*)(l), 16, 0, 0);
}

__global__ void diag_kernel(float* out, float v) { out[0] = v; }

__global__ void zero_i32(int* p, int n) {
  int i = blockIdx.x * 256 + threadIdx.x;
  if (i < n) p[i] = 0;
}

__global__ void conv_kernel(const float* __restrict__ in, __hip_bfloat16* __restrict__ out, int n) {
  for (int i = blockIdx.x * blockDim.x + threadIdx.x; i < n; i += gridDim.x * blockDim.x)
    out[i] = f2b(in[i]);
}

__global__ void conv4_kernel(const float* __restrict__ in, __hip_bfloat16* __restrict__ out, int n4) {
  int i = blockIdx.x * 256 + threadIdx.x;
  if (i >= n4) return;
  float4 v = ((const float4*)in)[i];
  ushort4 o;
  o.x = f2bu(v.x); o.y = f2bu(v.y); o.z = f2bu(v.z); o.w = f2bu(v.w);
  ((ushort4*)out)[i] = o;
}

__global__ void conv_gruw(const float* __restrict__ p0, const float* __restrict__ p1,
                          const float* __restrict__ p2, const float* __restrict__ p3,
                          __hip_bfloat16* __restrict__ out) {
  int idx = blockIdx.x * 256 + threadIdx.x;  // 786432 total
  int w = idx / 196608, r = idx - w * 196608;
  const float* s = (w == 0) ? p0 : (w == 1) ? p1 : (w == 2) ? p2 : p3;
  out[idx] = f2b(s[r]);
}

__global__ void conv_strided(const float* __restrict__ in, __hip_bfloat16* __restrict__ out,
                             int rows, int cols, int ld, int coff) {
  int idx = blockIdx.x * 256 + threadIdx.x;
  if (idx >= rows * cols) return;
  int r = idx / cols, c = idx - r * cols;
  out[idx] = f2b(in[(size_t)r * ld + coff + c]);
}

// ==================== burst-staged GEMM (tile 128x128, BK=128 phases) ====================
#define EPI_ESED 0
#define EPI_OUT  1

template <int EPI, bool DUAL>
__global__ __launch_bounds__(256, 2) void gemmF(
    const __hip_bfloat16* __restrict__ A1, const __hip_bfloat16* __restrict__ B1,
    const __hip_bfloat16* __restrict__ A2, const __hip_bfloat16* __restrict__ B2,
    void* __restrict__ Cv, int M, int N,
    const float* __restrict__ bi, const float* __restrict__ bh,
    float* __restrict__ ESp, float* __restrict__ EDp) {
  __shared__ __align__(16) short smem[32768];  // A[128][128] + B[128][128]
  const int tid = threadIdx.x;
  const int wid = tid >> 6, lane = tid & 63;

  // XCD-chunked bijective swizzle (m204)
  const int NW = gridDim.x * gridDim.y;
  const int wg = blockIdx.x + gridDim.x * blockIdx.y;
  const int q = NW >> 3, r8 = NW & 7;
  const int xcd = wg & 7, jj = wg >> 3;
  const int wid2 = (xcd < r8 ? xcd * (q + 1) : r8 * (q + 1) + (xcd - r8) * q) + jj;
  const int m0 = (wid2 / gridDim.x) * 128, n0 = (wid2 % gridDim.x) * 128;

  const int NPH = DUAL ? 4 : 2;
  f32x4 acc[2][8];
#pragma unroll
  for (int rf = 0; rf < 2; ++rf)
#pragma unroll
    for (int cf = 0; cf < 8; ++cf) acc[rf][cf] = (f32x4)0.f;

  for (int p = 0; p < NPH; ++p) {
    const __hip_bfloat16* A = (DUAL && p >= 2) ? A2 : A1;
    const __hip_bfloat16* B = (DUAL && p >= 2) ? B2 : B1;
    const int k0 = (p & 1) * 128;
#pragma unroll
    for (int i = 0; i < 8; ++i) {
      int qi = wid * 8 + i;
      int rl = qi * 4 + (lane >> 4);
      int sl = (lane & 15) ^ (rl & 15);
      gload16(A + (size_t)(m0 + rl) * 256 + k0 + sl * 8, &smem[qi * 512]);
      gload16(B + (size_t)(n0 + rl) * 256 + k0 + sl * 8, &smem[16384 + qi * 512]);
    }
    asm volatile("s_waitcnt vmcnt(0)" ::: "memory");
    __builtin_amdgcn_s_barrier();
    __builtin_amdgcn_sched_barrier(0);
#pragma unroll
    for (int kc = 0; kc < 4; ++kc) {
      const int sl = ((kc * 4 + (lane >> 4)) ^ (lane & 15)) * 8;
      short8 af[2];
#pragma unroll
      for (int rf = 0; rf < 2; ++rf)
        af[rf] = *(const short8*)&smem[(wid * 32 + rf * 16 + (lane & 15)) * 128 + sl];
#pragma unroll
      for (int cf = 0; cf < 8; ++cf) {
        short8 bf = *(const short8*)&smem[16384 + (cf * 16 + (lane & 15)) * 128 + sl];
#pragma unroll
        for (int rf = 0; rf < 2; ++rf)
          acc[rf][cf] = __builtin_amdgcn_mfma_f32_16x16x32_bf16(af[rf], bf, acc[rf][cf], 0, 0, 0);
      }
    }
    asm volatile("s_waitcnt lgkmcnt(0)" ::: "memory");
    __builtin_amdgcn_sched_barrier(0);
    __builtin_amdgcn_s_barrier();
  }

  const int rowb = m0 + wid * 32 + (lane >> 4) * 4;
  const int colb = n0 + (lane & 15);

  if constexpr (EPI == EPI_ESED) {
    const int head = n0 >> 7;
#pragma unroll
    for (int rf = 0; rf < 2; ++rf) {
#pragma unroll
      for (int rr = 0; rr < 4; ++rr) {
        const int row = rowb + rf * 16 + rr;
        float ps = 0.f, pd = 0.f;
#pragma unroll
        for (int cf = 0; cf < 8; ++cf) {
          const int col = colb + cf * 16;
          float v = acc[rf][cf][rr];
          if (row < M) ((__hip_bfloat16*)Cv)[(size_t)row * N + col] = f2b(v);
          ps += v * bi[col];
          pd += v * bh[col];
        }
#pragma unroll
        for (int o = 8; o >= 1; o >>= 1) {
          ps += __shfl_xor(ps, o, 64);
          pd += __shfl_xor(pd, o, 64);
        }
        if ((lane & 15) == 0 && row < M) {
          ESp[row * 2 + head] = ps;
          EDp[row * 2 + head] = pd;
        }
      }
    }
    return;
  }
#pragma unroll
  for (int rf = 0; rf < 2; ++rf)
#pragma unroll
    for (int cf = 0; cf < 8; ++cf) {
      const int col = colb + cf * 16;
#pragma unroll
      for (int rr = 0; rr < 4; ++rr) {
        const int row = rowb + rf * 16 + rr;
        if (row < M) ((float*)Cv)[(size_t)row * 256 + col] = acc[rf][cf][rr];
      }
    }
}

// ==================== gruF: fused GRU step, 128rows x 32cols, rf=2, direct stores ======
// r16: rf=1, 32KB, direct stores -> 144us @40% occ. r17: rf=2 + LDS-staged output ->
// 147us @31% (extra barrier + store tail serialized block exit). r18: rf=2 compute with
// r16's direct-store epilogue (no extra barrier). LDS 28KB, acc 16 f32x4.
template <int STEP>
__global__ __launch_bounds__(256) void gruF(
    const __hip_bfloat16* __restrict__ hF, const __hip_bfloat16* __restrict__ WiF,
    const __hip_bfloat16* __restrict__ hpF, const __hip_bfloat16* __restrict__ WhF,
    const float* __restrict__ biF, const float* __restrict__ bhF,
    __hip_bfloat16* __restrict__ outF,
    const __hip_bfloat16* __restrict__ hB, const __hip_bfloat16* __restrict__ WiB,
    const __hip_bfloat16* __restrict__ hpB, const __hip_bfloat16* __restrict__ WhB,
    const float* __restrict__ biB, const float* __restrict__ bhB,
    __hip_bfloat16* __restrict__ outB) {
  __shared__ __align__(16) short smem[14336];  // A[128][64] (8192) + B[96][64] (6144)
  const int tid = threadIdx.x;
  const int wid = tid >> 6, lane = tid & 63;

  // XCD swizzle; 16 slices (8 col x 2 dir) of one row-group are consecutive -> same XCD
  const int NW = gridDim.x * gridDim.y;   // 16 * 391 (divisible by 8)
  const int wg = blockIdx.x + gridDim.x * blockIdx.y;
  const int q = NW >> 3, r8 = NW & 7;
  const int xcd = wg & 7, jj = wg >> 3;
  const int wid2 = (xcd < r8 ? xcd * (q + 1) : r8 * (q + 1) + (xcd - r8) * q) + jj;
  const int bx2 = wid2 & 15;
  const int m0 = (wid2 >> 4) * 128;
  const int dir = bx2 >> 3;
  const int nc0 = (bx2 & 7) * 32;

  const __hip_bfloat16* Ah = dir ? hB : hF;
  const __hip_bfloat16* Wi = dir ? WiB : WiF;
  const __hip_bfloat16* Ahp = dir ? hpB : hpF;
  const __hip_bfloat16* Wh = dir ? WhB : WhF;
  const float* bi = dir ? biB : biF;
  const float* bh = dir ? bhB : bhF;
  __hip_bfloat16* outp = dir ? outB : outF;

  f32x4 acc[2][6];    // [rf][g*2+cf]: g 0=r, 1=z, 2=n_i
  f32x4 accNh[2][2];
#pragma unroll
  for (int rf = 0; rf < 2; ++rf) {
#pragma unroll
    for (int j = 0; j < 6; ++j) acc[rf][j] = (f32x4)0.f;
#pragma unroll
    for (int j = 0; j < 2; ++j) accNh[rf][j] = (f32x4)0.f;
  }

  auto stage = [&](const __hip_bfloat16* A, const __hip_bfloat16* W, int k0) {
    // A: 128 rows x 64 shorts = 16 issues (4/wave); issue = 8 rows x 8 perm-chunks
#pragma unroll
    for (int i = 0; i < 4; ++i) {
      int qi = wid * 4 + i;
      int rl = qi * 8 + (lane >> 3);
      int sl = (lane & 7) ^ (rl & 7);
      gload16(A + (size_t)(m0 + rl) * 256 + k0 + sl * 8, &smem[qi * 512]);
    }
    // B: 96 rows (3 gates x 32 cols) = 12 issues (3/wave); W row = (rl>>5)*256+nc0+(rl&31)
#pragma unroll
    for (int i = 0; i < 3; ++i) {
      int qi = wid * 3 + i;
      int rl = qi * 8 + (lane >> 3);
      int wrow = (rl >> 5) * 256 + nc0 + (rl & 31);
      int sl = (lane & 7) ^ (rl & 7);
      gload16(W + (size_t)wrow * 256 + k0 + sl * 8, &smem[8192 + qi * 512]);
    }
  };

  auto computeP = [&](auto PASSC) {
    constexpr int PASS = decltype(PASSC)::value;
#pragma unroll
    for (int kc = 0; kc < 2; ++kc) {
      short8 af[2];
#pragma unroll
      for (int rf = 0; rf < 2; ++rf) {
        const int arow = wid * 32 + rf * 16 + (lane & 15);
        const int pa = ((kc * 4 + (lane >> 4)) ^ (arow & 7)) * 8;
        af[rf] = *(const short8*)&smem[arow * 64 + pa];
      }
#pragma unroll
      for (int j = 0; j < 6; ++j) {
        const int brow = j * 16 + (lane & 15);
        const int pb = ((kc * 4 + (lane >> 4)) ^ (brow & 7)) * 8;
        short8 bf = *(const short8*)&smem[8192 + brow * 64 + pb];
#pragma unroll
        for (int rf = 0; rf < 2; ++rf) {
          if constexpr (PASS == 1) {
            if (j >= 4)
              accNh[rf][j - 4] = __builtin_amdgcn_mfma_f32_16x16x32_bf16(af[rf], bf, accNh[rf][j - 4], 0, 0, 0);
            else
              acc[rf][j] = __builtin_amdgcn_mfma_f32_16x16x32_bf16(af[rf], bf, acc[rf][j], 0, 0, 0);
          } else {
            acc[rf][j] = __builtin_amdgcn_mfma_f32_16x16x32_bf16(af[rf], bf, acc[rf][j], 0, 0, 0);
          }
        }
      }
    }
  };

  const int NPH = (STEP == 1) ? 4 : 8;
  for (int p = 0; p < NPH; ++p) {
    const int k0 = (p & 3) * 64;
    if (STEP == 2 && p >= 4) stage(Ahp, Wh, k0);
    else stage(Ah, Wi, k0);
    asm volatile("s_waitcnt vmcnt(0)" ::: "memory");
    __builtin_amdgcn_s_barrier();
    __builtin_amdgcn_sched_barrier(0);
    if (STEP == 2 && p >= 4) computeP(std::integral_constant<int, 1>{});
    else computeP(std::integral_constant<int, 0>{});
    asm volatile("s_waitcnt lgkmcnt(0)" ::: "memory");
    __builtin_amdgcn_sched_barrier(0);
    __builtin_amdgcn_s_barrier();
  }

  // epilogue: gate math, direct global stores (r16 style — no extra barrier)
#pragma unroll
  for (int cf = 0; cf < 2; ++cf) {
    const int col = nc0 + cf * 16 + (lane & 15);
    const float brz = bi[col] + bh[col];
    const float bzz = bi[256 + col] + bh[256 + col];
    const float bin = bi[512 + col];
    const float bhn = bh[512 + col];
#pragma unroll
    for (int rf = 0; rf < 2; ++rf) {
#pragma unroll
      for (int rr = 0; rr < 4; ++rr) {
        const int row = m0 + wid * 32 + rf * 16 + (lane >> 4) * 4 + rr;
        if (row >= NN) continue;
        float r_ = sigm(acc[rf][cf][rr] + brz);
        float z_ = sigm(acc[rf][2 + cf][rr] + bzz);
        if constexpr (STEP == 1) {
          float n_ = tanhf(acc[rf][4 + cf][rr] + bin + r_ * bhn);
          outp[(size_t)row * 256 + col] = f2b((1.f - z_) * n_);
        } else {
          float n_ = tanhf(acc[rf][4 + cf][rr] + bin + r_ * (accNh[rf][cf][rr] + bhn));
          float hp = b2f(Ahp[(size_t)row * 256 + col]);
          outp[(size_t)row * 256 + col] = f2b(hp + (1.f - z_) * n_ + z_ * hp);
        }
      }
    }
  }
}

// ---------------- CSR build ----------------
__global__ void hist_kernel(const int* __restrict__ dst, int* __restrict__ deg, int ne) {
  for (int e = blockIdx.x * blockDim.x + threadIdx.x; e < ne; e += gridDim.x * blockDim.x)
    atomicAdd(&deg[dst[e]], 1);
}

__global__ void scan1(const int* __restrict__ deg, int* __restrict__ bsum, int n) {
  __shared__ int sd[256];
  int idx = blockIdx.x * 256 + threadIdx.x;
  sd[threadIdx.x] = (idx < n) ? deg[idx] : 0;
  __syncthreads();
  for (int off = 128; off > 0; off >>= 1) {
    if (threadIdx.x < off) sd[threadIdx.x] += sd[threadIdx.x + off];
    __syncthreads();
  }
  if (threadIdx.x == 0) bsum[blockIdx.x] = sd[0];
}

__global__ void scan2(const int* __restrict__ bsum, int* __restrict__ boff, int nb) {
  __shared__ int s[256];
  int t = threadIdx.x;
  int v0 = (t < nb) ? bsum[t] : 0;
  s[t] = v0;
  __syncthreads();
  for (int off = 1; off < 256; off <<= 1) {
    int x = (t >= off) ? s[t - off] : 0;
    __syncthreads();
    s[t] += x;
    __syncthreads();
  }
  if (t < nb) boff[t] = s[t] - v0;
}

__global__ void scan3(const int* __restrict__ deg, const int* __restrict__ boff,
                      int* __restrict__ row_ptr, int* __restrict__ cursor, int n, int ne) {
  __shared__ int s[256];
  int t = threadIdx.x;
  int idx = blockIdx.x * 256 + t;
  int v = (idx < n) ? deg[idx] : 0;
  s[t] = v;
  __syncthreads();
  for (int off = 1; off < 256; off <<= 1) {
    int x = (t >= off) ? s[t - off] : 0;
    __syncthreads();
    s[t] += x;
    __syncthreads();
  }
  if (idx < n) {
    int val = boff[blockIdx.x] + s[t] - v;
    row_ptr[idx] = val;
    cursor[idx] = val;
  }
  if (idx == n) row_ptr[n] = ne;
}

__global__ void scatter_kernel(const int* __restrict__ src, const int* __restrict__ dst,
                               int* __restrict__ cursor, int* __restrict__ srcs, int ne) {
  for (int e = blockIdx.x * blockDim.x + threadIdx.x; e < ne; e += gridDim.x * blockDim.x) {
    int p = atomicAdd(&cursor[dst[e]], 1);
    srcs[p] = src[e];
  }
}

// ---------------- GAT aggregation: one wave per node ----------------
__device__ __forceinline__ void onl_upd(float& m, float& s, float v) {
  if (v <= m) {
    s += __expf(v - m);
  } else {
    s = s * __expf(m - v) + 1.f;
    m = v;
  }
}

__global__ __launch_bounds__(256) void gat_agg_wave(const int* __restrict__ row_ptr,
                                                    const int* __restrict__ srcs,
                                                    const float* __restrict__ es,
                                                    const float* __restrict__ ed,
                                                    const __hip_bfloat16* __restrict__ z,
                                                    __hip_bfloat16* __restrict__ hout) {
  int node = blockIdx.x * 4 + (threadIdx.x >> 6);
  int lane = threadIdx.x & 63;
  if (node >= NN) return;
  ushort4* outp = (ushort4*)&hout[(size_t)node * 256 + lane * 4];
  int start = row_ptr[node], end = row_ptr[node + 1];
  int deg = end - start;
  if (deg == 0) {
    *outp = make_ushort4(0, 0, 0, 0);
    return;
  }
  float ed0 = ed[node * 2], ed1 = ed[node * 2 + 1];
  int h = lane >> 5;
  float a0 = 0.f, a1 = 0.f, a2 = 0.f, a3 = 0.f;

  if (deg <= 64) {
    int sn = 0;
    float l0 = -1e30f, l1 = -1e30f;
    if (lane < deg) {
      sn = srcs[start + lane];
      float2 ee = *(const float2*)&es[sn * 2];
      l0 = leaky(ee.x + ed0);
      l1 = leaky(ee.y + ed1);
    }
    float m0 = l0, m1 = l1;
#pragma unroll
    for (int off = 32; off > 0; off >>= 1) {
      m0 = fmaxf(m0, __shfl_xor(m0, off, 64));
      m1 = fmaxf(m1, __shfl_xor(m1, off, 64));
    }
    float p0 = (lane < deg) ? __expf(l0 - m0) : 0.f;
    float p1 = (lane < deg) ? __expf(l1 - m1) : 0.f;
    float s0 = p0, s1 = p1;
#pragma unroll
    for (int off = 32; off > 0; off >>= 1) {
      s0 += __shfl_xor(s0, off, 64);
      s1 += __shfl_xor(s1, off, 64);
    }
    float w0 = p0 / s0, w1 = p1 / s1;
    const size_t zlo = lane * 4;
    int e = 0;
    for (; e + 4 <= deg; e += 4) {
      int sa = __shfl(sn, e, 64), sb = __shfl(sn, e + 1, 64);
      int sc = __shfl(sn, e + 2, 64), sd = __shfl(sn, e + 3, 64);
      float wa0 = __shfl(w0, e, 64),     wa1 = __shfl(w1, e, 64);
      float wb0 = __shfl(w0, e + 1, 64), wb1 = __shfl(w1, e + 1, 64);
      float wc0 = __shfl(w0, e + 2, 64), wc1 = __shfl(w1, e + 2, 64);
      float wd0 = __shfl(w0, e + 3, 64), wd1 = __shfl(w1, e + 3, 64);
      float wa = h ? wa1 : wa0;
      float wb = h ? wb1 : wb0;
      float wc = h ? wc1 : wc0;
      float wd = h ? wd1 : wd0;
      ushort4 za = *(const ushort4*)&z[(size_t)sa * 256 + zlo];
      ushort4 zb = *(const ushort4*)&z[(size_t)sb * 256 + zlo];
      ushort4 zc = *(const ushort4*)&z[(size_t)sc * 256 + zlo];
      ushort4 zd = *(const ushort4*)&z[(size_t)sd * 256 + zlo];
      a0 = fmaf(wa, bu2f(za.x), a0); a1 = fmaf(wa, bu2f(za.y), a1);
      a2 = fmaf(wa, bu2f(za.z), a2); a3 = fmaf(wa, bu2f(za.w), a3);
      a0 = fmaf(wb, bu2f(zb.x), a0); a1 = fmaf(wb, bu2f(zb.y), a1);
      a2 = fmaf(wb, bu2f(zb.z), a2); a3 = fmaf(wb, bu2f(zb.w), a3);
      a0 = fmaf(wc, bu2f(zc.x), a0); a1 = fmaf(wc, bu2f(zc.y), a1);
      a2 = fmaf(wc, bu2f(zc.z), a2); a3 = fmaf(wc, bu2f(zc.w), a3);
      a0 = fmaf(wd, bu2f(zd.x), a0); a1 = fmaf(wd, bu2f(zd.y), a1);
      a2 = fmaf(wd, bu2f(zd.z), a2); a3 = fmaf(wd, bu2f(zd.w), a3);
    }
    for (; e < deg; ++e) {
      int sa = __shfl(sn, e, 64);
      float wa0 = __shfl(w0, e, 64), wa1 = __shfl(w1, e, 64);
      float wa = h ? wa1 : wa0;
      ushort4 za = *(const ushort4*)&z[(size_t)sa * 256 + zlo];
      a0 = fmaf(wa, bu2f(za.x), a0); a1 = fmaf(wa, bu2f(za.y), a1);
      a2 = fmaf(wa, bu2f(za.z), a2); a3 = fmaf(wa, bu2f(za.w), a3);
    }
  } else {
    float m0 = -1e30f, s0 = 0.f, m1 = -1e30f, s1 = 0.f;
    for (int i = start + lane; i < end; i += 64) {
      int sn = srcs[i];
      float e0 = es[sn * 2], e1 = es[sn * 2 + 1];
      onl_upd(m0, s0, leaky(e0 + ed0));
      onl_upd(m1, s1, leaky(e1 + ed1));
    }
#pragma unroll
    for (int off = 32; off > 0; off >>= 1) {
      float om0 = __shfl_xor(m0, off, 64), os0 = __shfl_xor(s0, off, 64);
      float om1 = __shfl_xor(m1, off, 64), os1 = __shfl_xor(s1, off, 64);
      float mm = fmaxf(m0, om0);
      s0 = s0 * __expf(m0 - mm) + os0 * __expf(om0 - mm);
      m0 = mm;
      mm = fmaxf(m1, om1);
      s1 = s1 * __expf(m1 - mm) + os1 * __expf(om1 - mm);
      m1 = mm;
    }
    float rm = h ? m1 : m0;
    float rsi = 1.f / (h ? s1 : s0);
    float edh = h ? ed1 : ed0;
    for (int e = start; e < end; ++e) {
      int sa = srcs[e];
      float2 ee = *(const float2*)&es[sa * 2];
      float w = __expf(leaky((h ? ee.y : ee.x) + edh) - rm) * rsi;
      ushort4 zv = *(const ushort4*)&z[(size_t)sa * 256 + lane * 4];
      a0 = fmaf(w, bu2f(zv.x), a0); a1 = fmaf(w, bu2f(zv.y), a1);
      a2 = fmaf(w, bu2f(zv.z), a2); a3 = fmaf(w, bu2f(zv.w), a3);
    }
  }
  ushort4 o;
  o.x = f2bu(fmaxf(a0, 0.f));
  o.y = f2bu(fmaxf(a1, 0.f));
  o.z = f2bu(fmaxf(a2, 0.f));
  o.w = f2bu(fmaxf(a3, 0.f));
  *outp = o;
}

// ---------------- host ----------------
extern "C" void kernel_launch(void* const* d_in, const int* in_sizes, int n_in,
                              void* d_out, int out_size, void* d_ws, size_t ws_size,
                              hipStream_t stream) {
  const float* in_feat = (const float*)d_in[0];
  const int* srcp = (const int*)d_in[1];
  const int* dstp = (const int*)d_in[2];
  const float* W1 = (const float*)d_in[3];
  const float* as1 = (const float*)d_in[4];
  const float* ad1 = (const float*)d_in[5];
  const float* W2 = (const float*)d_in[6];
  const float* as2 = (const float*)d_in[7];
  const float* ad2 = (const float*)d_in[8];
  const float* wi_f = (const float*)d_in[9];
  const float* wh_f = (const float*)d_in[10];
  const float* bi_f = (const float*)d_in[11];
  const float* bh_f = (const float*)d_in[12];
  const float* wi_b = (const float*)d_in[13];
  const float* wh_b = (const float*)d_in[14];
  const float* bi_b = (const float*)d_in[15];
  const float* bh_b = (const float*)d_in[16];
  // d_in[17] = s_w: dead (softmax over a singleton axis == 1.0)
  const float* lin_w = (const float*)d_in[18];
  (void)in_sizes; (void)n_in; (void)out_size;

  const size_t UNIT = (size_t)MP * 256 * 2;
  char* ws = (char*)d_ws;
  size_t off = 0;
  auto take = [&](size_t bytes) -> void* {
    void* p = ws + off;
    off += (bytes + 255) & ~(size_t)255;
    return p;
  };
  __hip_bfloat16* U0 = (__hip_bfloat16*)take(UNIT);      // x, then fsum
  __hip_bfloat16* U1 = (__hip_bfloat16*)take(UNIT * 2);  // z (GAT), then bsum
  __hip_bfloat16* h1 = (__hip_bfloat16*)take(UNIT);
  __hip_bfloat16* h2 = (__hip_bfloat16*)take(UNIT);
  __hip_bfloat16* hpF = (__hip_bfloat16*)take(UNIT);     // f0
  __hip_bfloat16* hpB = (__hip_bfloat16*)take(UNIT);     // b1
  __hip_bfloat16* wW1 = (__hip_bfloat16*)take(65536 * 2);
  __hip_bfloat16* wW2 = (__hip_bfloat16*)take(65536 * 2);
  __hip_bfloat16* wif = (__hip_bfloat16*)take(196608 * 2);  // conv_gruw order: wif,whf,wib,whb
  __hip_bfloat16* whf = (__hip_bfloat16*)take(196608 * 2);
  __hip_bfloat16* wib = (__hip_bfloat16*)take(196608 * 2);
  __hip_bfloat16* whb = (__hip_bfloat16*)take(196608 * 2);
  __hip_bfloat16* wlinA = (__hip_bfloat16*)take(65536 * 2);
  __hip_bfloat16* wlinB = (__hip_bfloat16*)take(65536 * 2);
  int* deg = (int*)take((size_t)NN * 4);
  float* es1 = (float*)take((size_t)NN * 2 * 4);
  float* ed1 = (float*)take((size_t)NN * 2 * 4);
  float* es2 = (float*)take((size_t)NN * 2 * 4);
  float* ed2 = (float*)take((size_t)NN * 2 * 4);
  int* cursor = (int*)take((size_t)NN * 4);
  int* row_ptr = (int*)take((size_t)(NN + 1) * 4);
  int* bsum = (int*)take(256 * 4);
  int* boff = (int*)take(256 * 4);
  int* srcs = (int*)take((size_t)NE * 4);

  if (off > ws_size) {
    diag_kernel<<<1, 1, 0, stream>>>((float*)d_out, (float)ws_size);
    return;
  }

  // conversions
  conv4_kernel<<<12500, 256, 0, stream>>>(in_feat, U0, NN * 64);
  conv_kernel<<<256, 256, 0, stream>>>(W1, wW1, 65536);
  conv_kernel<<<256, 256, 0, stream>>>(W2, wW2, 65536);
  conv_gruw<<<3072, 256, 0, stream>>>(wi_f, wh_f, wi_b, wh_b, wif);
  conv_strided<<<256, 256, 0, stream>>>(lin_w, wlinA, 256, 256, 512, 0);
  conv_strided<<<256, 256, 0, stream>>>(lin_w, wlinB, 256, 256, 512, 256);

  // zero deg + es/ed
  {
    int zw = (int)(((char*)ed2 - (char*)deg) / 4) + NN * 2;
    zero_i32<<<(zw + 255) / 256, 256, 0, stream>>>(deg, zw);
  }
  hist_kernel<<<1024, 256, 0, stream>>>(dstp, deg, NE);
  scan1<<<NBLK, 256, 0, stream>>>(deg, bsum, NN);
  scan2<<<1, 256, 0, stream>>>(bsum, boff, NBLK);
  scan3<<<NBLK, 256, 0, stream>>>(deg, boff, row_ptr, cursor, NN, NE);
  scatter_kernel<<<1024, 256, 0, stream>>>(srcp, dstp, cursor, srcs, NE);

  dim3 g2(2, MP / 128), gGRU(16, MP / 128);

  // GAT layer 1
  gemmF<EPI_ESED, false><<<g2, 256, 0, stream>>>(U0, wW1, nullptr, nullptr, U1, NN, 256,
                                                 as1, ad1, es1, ed1);
  gat_agg_wave<<<12500, 256, 0, stream>>>(row_ptr, srcs, es1, ed1, U1, h1);
  // GAT layer 2
  gemmF<EPI_ESED, false><<<g2, 256, 0, stream>>>(h1, wW2, nullptr, nullptr, U1, NN, 256,
                                                 as2, ad2, es2, ed2);
  gat_agg_wave<<<12500, 256, 0, stream>>>(row_ptr, srcs, es2, ed2, U1, h2);

  // GRU step 1 (both directions): f0 = step(0,h1) -> hpF ; b1 = step(0,h2) -> hpB
  gruF<1><<<gGRU, 256, 0, stream>>>(
      h1, wif, nullptr, nullptr, bi_f, bh_f, hpF,
      h2, wib, nullptr, nullptr, bi_b, bh_b, hpB);
  // GRU step 2 (both directions): fsum = f0 + step(f0,h2) -> U0 ; bsum = b1 + step(b1,h1) -> U1
  gruF<2><<<gGRU, 256, 0, stream>>>(
      h2, wif, hpF, whf, bi_f, bh_f, U0,
      h1, wib, hpB, whb, bi_b, bh_b, U1);

  // out = fsum@linA^T + bsum@linB^T
  gemmF<EPI_OUT, true><<<g2, 256, 0, stream>>>(U0, wlinA, U1, wlinB, d_out, NN, 256,
                                               nullptr, nullptr, nullptr, nullptr);
}